// Round 11
// baseline (1220.162 us; speedup 1.0000x reference)
//
#include <hip/hip_runtime.h>

#define NB 8192
#define COMPS 4096
#define DIM 768
#define TB 384

typedef _Float16 half8_t __attribute__((ext_vector_type(8)));
typedef float floatx4 __attribute__((ext_vector_type(4)));
typedef unsigned short ushort4_t __attribute__((ext_vector_type(4)));
typedef unsigned long long ullx2 __attribute__((ext_vector_type(2)));
typedef int intx4 __attribute__((ext_vector_type(4)));

typedef __attribute__((address_space(1))) const void* gas_ptr;
typedef __attribute__((address_space(3))) void* las_ptr;

__device__ __forceinline__ void gl_lds16(const _Float16* g, _Float16* l) {
  __builtin_amdgcn_global_load_lds((gas_ptr)(const void*)g, (las_ptr)(void*)l, 16, 0, 0);
}

__device__ __forceinline__ unsigned long long pack_min(float v, int col) {
  unsigned u = __float_as_uint(v);
  u = (u & 0x80000000u) ? ~u : (u | 0x80000000u);
  return ((unsigned long long)u << 32) | (unsigned)col;
}

// ================= fused prep: e-split(hi) | c-split+cnorm | E+rE | zeroing ==
// ranges: [0,6144) e | [6144,10240) c | [10240,10304) E | [10304,10320) packed
//         [10320,10324) cnt | [10324,10328) rowsq | 10328 tk
#define PREP_GRID 10329
__global__ void k_prep(const float* __restrict__ e, const float* __restrict__ c,
                       const float* __restrict__ sigma,
                       _Float16* __restrict__ ehi,
                       _Float16* __restrict__ chi, _Float16* __restrict__ clo,
                       float* __restrict__ cnorm, float* __restrict__ E,
                       float* __restrict__ rE, int* __restrict__ cnt,
                       float* __restrict__ rowsq,
                       unsigned long long* __restrict__ packed,
                       unsigned int* __restrict__ tk) {
  int bx = blockIdx.x, t = threadIdx.x;
  if (bx < 6144) {
    int id = bx * 256 + t;
    float4 v = ((const float4*)e)[id];
    ushort4_t h;
    float xs[4] = {v.x, v.y, v.z, v.w};
#pragma unroll
    for (int q = 0; q < 4; ++q)
      h[q] = __builtin_bit_cast(unsigned short, (_Float16)xs[q]);
    ((ushort4_t*)ehi)[id] = h;
  } else if (bx < 10240) {
    int i = bx - 6144;
    float s = 0.f;
    if (t < 192) {
      float4 v = ((const float4*)c)[i * 192 + t];
      float xs[4] = {v.x, v.y, v.z, v.w};
      ushort4_t h, l;
#pragma unroll
      for (int q = 0; q < 4; ++q) {
        _Float16 hh = (_Float16)xs[q];
        _Float16 ll = (_Float16)(xs[q] - (float)hh);
        h[q] = __builtin_bit_cast(unsigned short, hh);
        l[q] = __builtin_bit_cast(unsigned short, ll);
        s = fmaf(xs[q], xs[q], s);
      }
      ((ushort4_t*)chi)[i * 192 + t] = h;
      ((ushort4_t*)clo)[i * 192 + t] = l;
    }
#pragma unroll
    for (int o = 32; o; o >>= 1) s += __shfl_down(s, o);
    __shared__ float red[3];
    if (t < 192 && (t & 63) == 0) red[t >> 6] = s;
    __syncthreads();
    if (t == 0) cnorm[i] = red[0] + red[1] + red[2];
  } else if (bx < 10304) {
    int i = bx - 10240;
    if (t < 64) {
      float sg = sigma[0];
      float inv = -1.0f / (2.0f * sg * sg);
      float d = (float)(i - t);
      float v = expf(d * d * inv);
      E[i * 64 + t] = v;
      float s = v;
#pragma unroll
      for (int o = 32; o; o >>= 1) s += __shfl_down(s, o);
      if (t == 0) rE[i] = s;
    }
  } else if (bx < 10320) {
    int id = (bx - 10304) * 256 + t;
    ullx2 f = {~0ULL, ~0ULL};
    ((ullx2*)packed)[id] = f;
  } else if (bx < 10324) {
    int id = (bx - 10320) * 256 + t;
    intx4 z = {0, 0, 0, 0};
    ((intx4*)cnt)[id] = z;
  } else if (bx < 10328) {
    int id = (bx - 10324) * 256 + t;
    floatx4 z = {0.f, 0.f, 0.f, 0.f};
    ((floatx4*)rowsq)[id] = z;
  } else {
    if (t < 64) tk[t] = 0u;
  }
}

// ---------------- GEMM1: dist + fused argmin (BK=64, XOR swizzle) ----------
// dist' = ||c||^2 - 2*(ehi.chi + ehi.clo)  [elo dropped; validated R10:
// absmax 4.9e-4, far under 773]. 3 LDS planes (48 KB). UNCHANGED from R10.
__launch_bounds__(256)
__global__ void k_gemm1(const _Float16* __restrict__ ehi,
                        const _Float16* __restrict__ chi, const _Float16* __restrict__ clo,
                        const float* __restrict__ cnorm,
                        unsigned long long* __restrict__ packed) {
  __shared__ _Float16 lds[3][128 * 64];   // 48 KB: 0=Ah(ehi) 1=Bh(chi) 2=Bl(clo)
  int tid = threadIdx.x;
  int lane = tid & 63, w = tid >> 6;
  int wr = w >> 1, wc = w & 1;
  int g = lane >> 4, rl = lane & 15;
  int i0 = blockIdx.x * 128, j0 = blockIdx.y * 128;

  int lr = lane >> 3, lc = lane & 7;
  int cch = lc ^ lr;                           // inverse swizzle (rule #21)
  const _Float16* gsrc = ehi;
  _Float16* dst = &lds[0][0];
  if (w == 0)      { gsrc = ehi + (size_t)i0 * DIM; dst = &lds[0][0]; }
  else if (w == 1) { gsrc = chi + (size_t)j0 * DIM; dst = &lds[1][0]; }
  else if (w == 2) { gsrc = clo + (size_t)j0 * DIM; dst = &lds[2][0]; }
  gsrc += (size_t)lr * DIM + cch * 8;
  dst += lane * 8;

  floatx4 acc[4][4] = {};

  for (int kt = 0; kt < DIM; kt += 64) {
    __syncthreads();
    if (w < 3) {
#pragma unroll
      for (int q = 0; q < 16; ++q)
        gl_lds16(gsrc + kt + (size_t)(q * 8) * DIM, dst + q * 512);
    }
    __syncthreads();

#pragma unroll
    for (int s = 0; s < 2; ++s) {
      half8_t ah[4];
#pragma unroll
      for (int m = 0; m < 4; ++m) {
        int r = wr * 64 + m * 16 + rl;
        int p = (s * 4 + g) ^ (rl & 7);
        ah[m] = *(half8_t*)&lds[0][r * 64 + p * 8];
      }
#pragma unroll
      for (int n = 0; n < 4; ++n) {
        int r = wc * 64 + n * 16 + rl;
        int p = (s * 4 + g) ^ (rl & 7);
        half8_t bh = *(half8_t*)&lds[1][r * 64 + p * 8];
        half8_t bl = *(half8_t*)&lds[2][r * 64 + p * 8];
#pragma unroll
        for (int m = 0; m < 4; ++m) {
          acc[m][n] = __builtin_amdgcn_mfma_f32_16x16x32_f16(ah[m], bh, acc[m][n], 0, 0, 0);
          acc[m][n] = __builtin_amdgcn_mfma_f32_16x16x32_f16(ah[m], bl, acc[m][n], 0, 0, 0);
        }
      }
    }
  }

  float cn[4];
#pragma unroll
  for (int n = 0; n < 4; ++n) cn[n] = cnorm[j0 + wc * 64 + n * 16 + rl];

#pragma unroll
  for (int m = 0; m < 4; ++m) {
#pragma unroll
    for (int j = 0; j < 4; ++j) {
      int row = i0 + wr * 64 + m * 16 + g * 4 + j;
      float best = 3.0e38f;
      int bcol = 0;
#pragma unroll
      for (int n = 0; n < 4; ++n) {
        float d = fmaf(-2.0f, acc[m][n][j], cn[n]);
        int col = j0 + wc * 64 + n * 16 + rl;
        if (d < best) { best = d; bcol = col; }
      }
      unsigned long long pk = pack_min(best, bcol);
#pragma unroll
      for (int o = 1; o < 16; o <<= 1) {
        unsigned long long other = __shfl_xor(pk, o);
        if (other < pk) pk = other;
      }
      if (rl == 0) atomicMin(&packed[row], pk);
    }
  }
}

// ---------------- grid barrier (TB blocks co-resident) ----------------
__device__ __forceinline__ void gbar(unsigned int* tkslot) {
  __syncthreads();   // drains vmcnt: all prior (atomic) writes at coherent pt
  if (threadIdx.x == 0) {
    __hip_atomic_fetch_add(tkslot, 1u, __ATOMIC_RELEASE, __HIP_MEMORY_SCOPE_AGENT);
    while (__hip_atomic_load(tkslot, __ATOMIC_ACQUIRE, __HIP_MEMORY_SCOPE_AGENT)
           < (unsigned)TB) {
      __builtin_amdgcn_s_sleep(8);
    }
  }
  __syncthreads();
}

// == tail megakernel: count|scan|fill|gather+T1|wnum+delta, 4 grid barriers ==
// All cross-block data goes through device-coherent atomics (no dirty-L2
// cross-XCD hazard); serial phases (count/scan/fill) are ~us, heavy phases
// (gather->T1, wnum) run at full 384-block parallelism.
__launch_bounds__(256, 2)
__global__ void k_tail(const float* __restrict__ e,
                       const unsigned long long* __restrict__ packed,
                       const float* __restrict__ cont, const float* __restrict__ E,
                       const float* __restrict__ rE, int* __restrict__ cnt,
                       int* __restrict__ offs, int* __restrict__ cursor,
                       int* __restrict__ rows, float* __restrict__ T1,
                       float* __restrict__ rowsq, float* __restrict__ out,
                       unsigned int* __restrict__ tk) {
  __shared__ float S[64 * 128];   // 32 KB slab (avg, then T1)
  __shared__ float Esh[64 * 64];  // 16 KB
  int bid = blockIdx.x, t = threadIdx.x;
  int gtid = bid * 256 + t;

  // ---- phase 1: count BMU histogram ----
  if (gtid < NB) {
    int idx = (int)(packed[gtid] & 0xffffffffULL);
    atomicAdd(&cnt[idx], 1);
  }
#pragma unroll
  for (int it = 0; it < 4; ++it) {
    int id = t + 256 * it;
    ((floatx4*)Esh)[id] = ((const floatx4*)E)[id];
  }
  gbar(&tk[0]);

  // ---- phase 2: exclusive scan (block 0 only) -> offs, cursor ----
  if (bid == 0) {
    int v[16];
    int tot = 0;
#pragma unroll
    for (int q = 0; q < 16; ++q) { v[q] = cnt[t * 16 + q]; tot += v[q]; }
    int lane = t & 63, wid = t >> 6;
    int s = tot;
#pragma unroll
    for (int o = 1; o < 64; o <<= 1) {
      int u = __shfl_up(s, o);
      if (lane >= o) s += u;
    }
    __shared__ int wt[4];
    if (lane == 63) wt[wid] = s;
    __syncthreads();
    int add = 0;
    for (int w2 = 0; w2 < wid; ++w2) add += wt[w2];
    int run = add + s - tot;
#pragma unroll
    for (int q = 0; q < 16; ++q) {
      __hip_atomic_store(&offs[t * 16 + q], run, __ATOMIC_RELAXED,
                         __HIP_MEMORY_SCOPE_AGENT);
      __hip_atomic_store(&cursor[t * 16 + q], run, __ATOMIC_RELAXED,
                         __HIP_MEMORY_SCOPE_AGENT);
      run += v[q];
    }
  }
  gbar(&tk[1]);

  // ---- phase 3: fill row lists ----
  if (gtid < NB) {
    int idx = (int)(packed[gtid] & 0xffffffffULL);
    int pos = atomicAdd(&cursor[idx], 1);
    __hip_atomic_store(&rows[pos], gtid, __ATOMIC_RELAXED,
                       __HIP_MEMORY_SCOPE_AGENT);
  }
  gbar(&tk[2]);

  // ---- phase 4: gather avg into LDS slab + T1 = E-rows x S ----
  {
    int a = bid / 6, db = bid % 6;
    int wv = t >> 6, lane = t & 63;
    const float2* e2 = (const float2*)e;
    const float2* c2 = (const float2*)cont;
#pragma unroll 1
    for (int rr = 0; rr < 16; ++rr) {
      int r = wv * 16 + rr;
      int comp = a * 64 + r;
      int n = cnt[comp];
      float2 acc2 = {0.f, 0.f};
      if (n == 0) {
        acc2 = c2[(size_t)comp * 384 + db * 64 + lane];
      } else {
        int o0 = __hip_atomic_load(&offs[comp], __ATOMIC_RELAXED,
                                   __HIP_MEMORY_SCOPE_AGENT);
        for (int k = 0; k < n; ++k) {
          int i = __hip_atomic_load(&rows[o0 + k], __ATOMIC_RELAXED,
                                    __HIP_MEMORY_SCOPE_AGENT);
          float2 ev = e2[(size_t)i * 384 + db * 64 + lane];
          acc2.x += ev.x; acc2.y += ev.y;
        }
        float inv = 1.0f / (float)n;
        acc2.x *= inv; acc2.y *= inv;
      }
      S[r * 128 + lane * 2] = acc2.x;
      S[r * 128 + lane * 2 + 1] = acc2.y;
    }
    __syncthreads();

    int d4 = t & 31, b0 = (t >> 5) * 8;
    floatx4 acc[8] = {};
    for (int bp = 0; bp < 64; ++bp) {
      floatx4 sv = ((floatx4*)S)[bp * 32 + d4];
#pragma unroll
      for (int b = 0; b < 8; ++b)
        acc[b] += Esh[(b0 + b) * 64 + bp] * sv;
    }
#pragma unroll
    for (int b = 0; b < 8; ++b) {
      size_t base = ((size_t)(a * 64 + b0 + b) * 192 + db * 32 + d4) * 4;
#pragma unroll
      for (int q = 0; q < 4; ++q)
        __hip_atomic_store(&T1[base + q], acc[b][q], __ATOMIC_RELAXED,
                           __HIP_MEMORY_SCOPE_AGENT);
    }
  }
  gbar(&tk[3]);

  // ---- phase 5: num = E @ T1 ; update/where ; rowsq ; fused delta ----
  {
    int b = bid / 6, db = bid % 6;
#pragma unroll
    for (int it = 0; it < 8; ++it) {
      int id = t + 256 * it;
      int ap = id >> 5, c4 = id & 31;
      ((floatx4*)S)[id] =
          ((const floatx4*)T1)[(size_t)(ap * 64 + b) * 192 + db * 32 + c4];
    }
    __syncthreads();

    int d4 = t & 31, a0 = (t >> 5) * 8;
    floatx4 acc[8] = {};
    for (int ap = 0; ap < 64; ++ap) {
      floatx4 tv = ((floatx4*)S)[ap * 32 + d4];
#pragma unroll
      for (int a = 0; a < 8; ++a)
        acc[a] += Esh[(a0 + a) * 64 + ap] * tv;
    }

    float rb = rE[b];
    float sq[8];
#pragma unroll
    for (int a = 0; a < 8; ++a) {
      int comp = (a0 + a) * 64 + b;
      bool used = cnt[comp] > 0;
      floatx4 cv = ((const floatx4*)cont)[(size_t)comp * 192 + db * 32 + d4];
      floatx4 val;
      if (used) val = acc[a] * (1.0f / (rE[a0 + a] * rb));
      else val = cv;
      size_t base = 1 + (size_t)comp * DIM + db * 128 + d4 * 4;
      out[base] = val[0]; out[base + 1] = val[1];
      out[base + 2] = val[2]; out[base + 3] = val[3];
      floatx4 df = val - cv;
      sq[a] = df[0] * df[0] + df[1] * df[1] + df[2] * df[2] + df[3] * df[3];
    }
#pragma unroll
    for (int a = 0; a < 8; ++a) {
#pragma unroll
      for (int o = 1; o < 32; o <<= 1) sq[a] += __shfl_xor(sq[a], o);
    }
    if (d4 == 0) {
#pragma unroll
      for (int a = 0; a < 8; ++a)
        unsafeAtomicAdd(&rowsq[(a0 + a) * 64 + b], sq[a]);
    }

    // fused delta: last block reduces rowsq
    __shared__ unsigned int lastflag;
    __syncthreads();
    if (t == 0) {
      unsigned int old = __hip_atomic_fetch_add(&tk[4], 1u, __ATOMIC_ACQ_REL,
                                                __HIP_MEMORY_SCOPE_AGENT);
      lastflag = (old == (unsigned)TB - 1u) ? 1u : 0u;
    }
    __syncthreads();
    if (lastflag) {
      double s = 0.0;
      for (int c2i = t; c2i < COMPS; c2i += 256) {
        float r = __hip_atomic_load(&rowsq[c2i], __ATOMIC_RELAXED,
                                    __HIP_MEMORY_SCOPE_AGENT);
        s += sqrt((double)r);
      }
#pragma unroll
      for (int o = 32; o; o >>= 1) s += __shfl_down(s, o);
      __shared__ double red[4];
      if ((t & 63) == 0) red[t >> 6] = s;
      __syncthreads();
      if (t == 0) out[0] = (float)(red[0] + red[1] + red[2] + red[3]);
    }
  }
}

extern "C" void kernel_launch(void* const* d_in, const int* in_sizes, int n_in,
                              void* d_out, int out_size, void* d_ws, size_t ws_size,
                              hipStream_t stream) {
  const float* e = (const float*)d_in[0];       // [8192, 768]
  const float* cont = (const float*)d_in[1];    // [64, 64, 768]
  // d_in[2] (grid_dists) not read: W = E (x) E separable
  const float* sigma = (const float*)d_in[3];   // [1]
  float* out = (float*)d_out;                   // [1 + 4096*768]

  char* ws = (char*)d_ws;
  size_t off = 0;
  auto take = [&](size_t bytes) { char* p = ws + off; off += (bytes + 255) & ~(size_t)255; return p; };

  unsigned long long* packed = (unsigned long long*)take(NB * 8);
  int* cnt    = (int*)take(COMPS * 4);
  int* offs   = (int*)take(COMPS * 4);
  int* cursor = (int*)take(COMPS * 4);
  int* rows   = (int*)take(NB * 4);
  float* rowsq = (float*)take(COMPS * 4);
  float* cnorm = (float*)take(COMPS * 4);
  float* E     = (float*)take(64 * 64 * 4);
  float* rE    = (float*)take(64 * 4);
  unsigned int* tk = (unsigned int*)take(256);
  // union region: {ehi, chi, clo} during GEMM1; T1 aliases chi+clo after
  char* U = take((size_t)NB * DIM * 2 + (size_t)COMPS * DIM * 2 * 2);
  _Float16* ehi = (_Float16*)U;
  _Float16* chi = (_Float16*)(U + (size_t)NB * DIM * 2);
  _Float16* clo = (_Float16*)(U + (size_t)NB * DIM * 2 + (size_t)COMPS * DIM * 2);
  float* T1 = (float*)(U + (size_t)NB * DIM * 2);   // 12.58MB = chi+clo region

  k_prep<<<PREP_GRID, 256, 0, stream>>>(e, cont, sigma, ehi, chi, clo,
                                        cnorm, E, rE, cnt, rowsq, packed, tk);
  k_gemm1<<<dim3(NB / 128, COMPS / 128), 256, 0, stream>>>(ehi, chi, clo, cnorm, packed);
  k_tail<<<TB, 256, 0, stream>>>(e, packed, cont, E, rE, cnt, offs, cursor,
                                 rows, T1, rowsq, out, tk);
}

// Round 12
// 298.865 us; speedup vs baseline: 4.0827x; 4.0827x over previous
//
#include <hip/hip_runtime.h>
#include <hip/hip_fp16.h>

#define NB 8192
#define COMPS 4096
#define DIM 768

typedef _Float16 half8_t __attribute__((ext_vector_type(8)));
typedef float floatx4 __attribute__((ext_vector_type(4)));
typedef unsigned short ushort4_t __attribute__((ext_vector_type(4)));
typedef unsigned long long ullx2 __attribute__((ext_vector_type(2)));

typedef __attribute__((address_space(1))) const void* gas_ptr;
typedef __attribute__((address_space(3))) void* las_ptr;

__device__ __forceinline__ void gl_lds16(const _Float16* g, _Float16* l) {
  __builtin_amdgcn_global_load_lds((gas_ptr)(const void*)g, (las_ptr)(void*)l, 16, 0, 0);
}

__device__ __forceinline__ unsigned long long pack_min(float v, int col) {
  unsigned u = __float_as_uint(v);
  u = (u & 0x80000000u) ? ~u : (u | 0x80000000u);
  return ((unsigned long long)u << 32) | (unsigned)col;
}

// ================= fused prep: e-split(hi) | c-split+cnorm | E+rE | zeroing ==
// ranges: [0,6144) e | [6144,10240) c | [10240,10304) E | [10304,11840) sums=0
//         [11840,11856) packed | [11856,11860) freq | [11860,11864) rowsq
//         11864 done
#define PREP_GRID 11865
__global__ void k_prep(const float* __restrict__ e, const float* __restrict__ c,
                       const float* __restrict__ sigma,
                       _Float16* __restrict__ ehi,
                       _Float16* __restrict__ chi, _Float16* __restrict__ clo,
                       float* __restrict__ cnorm, float* __restrict__ E,
                       float* __restrict__ rE, _Float16* __restrict__ sums,
                       float* __restrict__ freq, float* __restrict__ rowsq,
                       unsigned long long* __restrict__ packed,
                       unsigned int* __restrict__ done) {
  int bx = blockIdx.x, t = threadIdx.x;
  if (bx < 6144) {
    int id = bx * 256 + t;
    float4 v = ((const float4*)e)[id];
    ushort4_t h;
    float xs[4] = {v.x, v.y, v.z, v.w};
#pragma unroll
    for (int q = 0; q < 4; ++q)
      h[q] = __builtin_bit_cast(unsigned short, (_Float16)xs[q]);
    ((ushort4_t*)ehi)[id] = h;
  } else if (bx < 10240) {
    int i = bx - 6144;
    float s = 0.f;
    if (t < 192) {
      float4 v = ((const float4*)c)[i * 192 + t];
      float xs[4] = {v.x, v.y, v.z, v.w};
      ushort4_t h, l;
#pragma unroll
      for (int q = 0; q < 4; ++q) {
        _Float16 hh = (_Float16)xs[q];
        _Float16 ll = (_Float16)(xs[q] - (float)hh);
        h[q] = __builtin_bit_cast(unsigned short, hh);
        l[q] = __builtin_bit_cast(unsigned short, ll);
        s = fmaf(xs[q], xs[q], s);
      }
      ((ushort4_t*)chi)[i * 192 + t] = h;
      ((ushort4_t*)clo)[i * 192 + t] = l;
    }
#pragma unroll
    for (int o = 32; o; o >>= 1) s += __shfl_down(s, o);
    __shared__ float red[3];
    if (t < 192 && (t & 63) == 0) red[t >> 6] = s;
    __syncthreads();
    if (t == 0) cnorm[i] = red[0] + red[1] + red[2];
  } else if (bx < 10304) {
    int i = bx - 10240;
    if (t < 64) {
      float sg = sigma[0];
      float inv = -1.0f / (2.0f * sg * sg);
      float d = (float)(i - t);
      float v = expf(d * d * inv);
      E[i * 64 + t] = v;
      float s = v;
#pragma unroll
      for (int o = 32; o; o >>= 1) s += __shfl_down(s, o);
      if (t == 0) rE[i] = s;
    }
  } else if (bx < 11840) {
    int id = (bx - 10304) * 256 + t;
    floatx4 z = {0.f, 0.f, 0.f, 0.f};
    ((floatx4*)sums)[id] = z;          // 16B units over f16 buffer
  } else if (bx < 11856) {
    int id = (bx - 11840) * 256 + t;
    ullx2 f = {~0ULL, ~0ULL};
    ((ullx2*)packed)[id] = f;
  } else if (bx < 11860) {
    int id = (bx - 11856) * 256 + t;
    floatx4 z = {0.f, 0.f, 0.f, 0.f};
    ((floatx4*)freq)[id] = z;
  } else if (bx < 11864) {
    int id = (bx - 11860) * 256 + t;
    floatx4 z = {0.f, 0.f, 0.f, 0.f};
    ((floatx4*)rowsq)[id] = z;
  } else {
    if (t == 0) *done = 0u;
  }
}

// ---------------- GEMM1: dist + fused argmin (BK=64, XOR swizzle) ----------
// dist' = ||c||^2 - 2*(ehi.chi + ehi.clo). UNCHANGED from R10 (105.5 us,
// conflicts 0, absmax 4.9e-4 validated).
__launch_bounds__(256)
__global__ void k_gemm1(const _Float16* __restrict__ ehi,
                        const _Float16* __restrict__ chi, const _Float16* __restrict__ clo,
                        const float* __restrict__ cnorm,
                        unsigned long long* __restrict__ packed) {
  __shared__ _Float16 lds[3][128 * 64];   // 48 KB: 0=Ah(ehi) 1=Bh(chi) 2=Bl(clo)
  int tid = threadIdx.x;
  int lane = tid & 63, w = tid >> 6;
  int wr = w >> 1, wc = w & 1;
  int g = lane >> 4, rl = lane & 15;
  int i0 = blockIdx.x * 128, j0 = blockIdx.y * 128;

  int lr = lane >> 3, lc = lane & 7;
  int cch = lc ^ lr;                           // inverse swizzle (rule #21)
  const _Float16* gsrc = ehi;
  _Float16* dst = &lds[0][0];
  if (w == 0)      { gsrc = ehi + (size_t)i0 * DIM; dst = &lds[0][0]; }
  else if (w == 1) { gsrc = chi + (size_t)j0 * DIM; dst = &lds[1][0]; }
  else if (w == 2) { gsrc = clo + (size_t)j0 * DIM; dst = &lds[2][0]; }
  gsrc += (size_t)lr * DIM + cch * 8;
  dst += lane * 8;

  floatx4 acc[4][4] = {};

  for (int kt = 0; kt < DIM; kt += 64) {
    __syncthreads();
    if (w < 3) {
#pragma unroll
      for (int q = 0; q < 16; ++q)
        gl_lds16(gsrc + kt + (size_t)(q * 8) * DIM, dst + q * 512);
    }
    __syncthreads();

#pragma unroll
    for (int s = 0; s < 2; ++s) {
      half8_t ah[4];
#pragma unroll
      for (int m = 0; m < 4; ++m) {
        int r = wr * 64 + m * 16 + rl;
        int p = (s * 4 + g) ^ (rl & 7);
        ah[m] = *(half8_t*)&lds[0][r * 64 + p * 8];
      }
#pragma unroll
      for (int n = 0; n < 4; ++n) {
        int r = wc * 64 + n * 16 + rl;
        int p = (s * 4 + g) ^ (rl & 7);
        half8_t bh = *(half8_t*)&lds[1][r * 64 + p * 8];
        half8_t bl = *(half8_t*)&lds[2][r * 64 + p * 8];
#pragma unroll
        for (int m = 0; m < 4; ++m) {
          acc[m][n] = __builtin_amdgcn_mfma_f32_16x16x32_f16(ah[m], bh, acc[m][n], 0, 0, 0);
          acc[m][n] = __builtin_amdgcn_mfma_f32_16x16x32_f16(ah[m], bl, acc[m][n], 0, 0, 0);
        }
      }
    }
  }

  float cn[4];
#pragma unroll
  for (int n = 0; n < 4; ++n) cn[n] = cnorm[j0 + wc * 64 + n * 16 + rl];

#pragma unroll
  for (int m = 0; m < 4; ++m) {
#pragma unroll
    for (int j = 0; j < 4; ++j) {
      int row = i0 + wr * 64 + m * 16 + g * 4 + j;
      float best = 3.0e38f;
      int bcol = 0;
#pragma unroll
      for (int n = 0; n < 4; ++n) {
        float d = fmaf(-2.0f, acc[m][n][j], cn[n]);
        int col = j0 + wc * 64 + n * 16 + rl;
        if (d < best) { best = d; bcol = col; }
      }
      unsigned long long pk = pack_min(best, bcol);
#pragma unroll
      for (int o = 1; o < 16; o <<= 1) {
        unsigned long long other = __shfl_xor(pk, o);
        if (other < pk) pk = other;
      }
      if (rl == 0) atomicMin(&packed[row], pk);
    }
  }
}

// ------- scatter: freq (fp32) + per-comp sums via packed f16 atomics -------
// Reads ehi (f16, L2/L3-resident), 384 half2 pk-atomics per row (was 768 fp32).
__global__ void k_scatter(const _Float16* __restrict__ ehi,
                          const unsigned long long* __restrict__ packed,
                          float* __restrict__ freq, __half2* __restrict__ sums) {
  int i = blockIdx.x, t = threadIdx.x;   // 192 threads
  int idx = (int)(packed[i] & 0xffffffffULL);
  if (t == 0) unsafeAtomicAdd(&freq[idx], 1.0f);
  const __half2* ev = (const __half2*)(ehi + (size_t)i * DIM);
  __half2* srow = sums + (size_t)idx * (DIM / 2);
#pragma unroll
  for (int r = 0; r < 2; ++r) {
    int d = t + 192 * r;
    unsafeAtomicAdd(&srow[d], ev[d]);
  }
}

// ---------------- T1[a][b][d] = sum_b' E[b,b'] * avg[(a,b')][d] ------------
// avg computed on the fly from f16 sums / fp32 freq / cont fallback.
__global__ void k_t1(const _Float16* __restrict__ sums, const float* __restrict__ freq,
                     const float* __restrict__ cont, const float* __restrict__ E,
                     float* __restrict__ T1) {
  __shared__ float S[64 * 128];   // 32 KB: avg slab [b'][d]
  __shared__ float Esh[64 * 64];  // 16 KB
  int a = blockIdx.x, db = blockIdx.y, t = threadIdx.x;
#pragma unroll
  for (int it = 0; it < 8; ++it) {
    int id = t + 256 * it;
    int row = id >> 5, c4 = id & 31;
    int comp = a * 64 + row;
    float f = freq[comp];
    floatx4 v;
    if (f > 0.f) {
      const __half2* sp = (const __half2*)(sums + (size_t)comp * DIM) + db * 64 + c4 * 2;
      float2 p0 = __half22float2(sp[0]);
      float2 p1 = __half22float2(sp[1]);
      float inv = 1.0f / f;
      v[0] = p0.x * inv; v[1] = p0.y * inv;
      v[2] = p1.x * inv; v[3] = p1.y * inv;
    } else {
      v = ((const floatx4*)cont)[(size_t)comp * 192 + db * 32 + c4];
    }
    ((floatx4*)S)[id] = v;
  }
#pragma unroll
  for (int it = 0; it < 4; ++it) {
    int id = t + 256 * it;
    ((floatx4*)Esh)[id] = ((const floatx4*)E)[id];
  }
  __syncthreads();

  int d4 = t & 31, b0 = (t >> 5) * 8;
  floatx4 acc[8] = {};
  for (int bp = 0; bp < 64; ++bp) {
    floatx4 sv = ((floatx4*)S)[bp * 32 + d4];
#pragma unroll
    for (int b = 0; b < 8; ++b)
      acc[b] += Esh[(b0 + b) * 64 + bp] * sv;
  }
#pragma unroll
  for (int b = 0; b < 8; ++b)
    ((floatx4*)T1)[(size_t)(a * 64 + b0 + b) * 192 + db * 32 + d4] = acc[b];
}

// ------ num = sum_a' E[a,a'] T1[a'][b][d]; update + rowsq + fused delta ----
__global__ void k_wnum(const float* __restrict__ T1, const float* __restrict__ E,
                       const float* __restrict__ rE, const float* __restrict__ freq,
                       const float* __restrict__ cont, float* __restrict__ out,
                       float* __restrict__ rowsq, unsigned int* __restrict__ done) {
  __shared__ float S[64 * 128];   // T1 slab [a'][d]
  __shared__ float Esh[64 * 64];
  int b = blockIdx.x, db = blockIdx.y, t = threadIdx.x;
#pragma unroll
  for (int it = 0; it < 8; ++it) {
    int id = t + 256 * it;
    int ap = id >> 5, c4 = id & 31;
    ((floatx4*)S)[id] = ((const floatx4*)T1)[(size_t)(ap * 64 + b) * 192 + db * 32 + c4];
  }
#pragma unroll
  for (int it = 0; it < 4; ++it) {
    int id = t + 256 * it;
    ((floatx4*)Esh)[id] = ((const floatx4*)E)[id];
  }
  __syncthreads();

  int d4 = t & 31, a0 = (t >> 5) * 8;
  floatx4 acc[8] = {};
  for (int ap = 0; ap < 64; ++ap) {
    floatx4 tv = ((floatx4*)S)[ap * 32 + d4];
#pragma unroll
    for (int a = 0; a < 8; ++a)
      acc[a] += Esh[(a0 + a) * 64 + ap] * tv;
  }

  float rb = rE[b];
  float sq[8];
#pragma unroll
  for (int a = 0; a < 8; ++a) {
    int comp = (a0 + a) * 64 + b;
    bool used = freq[comp] > 0.f;
    floatx4 cv = ((const floatx4*)cont)[(size_t)comp * 192 + db * 32 + d4];
    floatx4 val;
    if (used) val = acc[a] * (1.0f / (rE[a0 + a] * rb));
    else val = cv;
    size_t base = 1 + (size_t)comp * DIM + db * 128 + d4 * 4;
    out[base] = val[0]; out[base + 1] = val[1];
    out[base + 2] = val[2]; out[base + 3] = val[3];
    floatx4 df = val - cv;
    sq[a] = df[0] * df[0] + df[1] * df[1] + df[2] * df[2] + df[3] * df[3];
  }
#pragma unroll
  for (int a = 0; a < 8; ++a) {
#pragma unroll
    for (int o = 1; o < 32; o <<= 1) sq[a] += __shfl_xor(sq[a], o);
  }
  if (d4 == 0) {
#pragma unroll
    for (int a = 0; a < 8; ++a)
      unsafeAtomicAdd(&rowsq[(a0 + a) * 64 + b], sq[a]);
  }

  // fused delta: last of the 384 blocks reduces rowsq
  __shared__ unsigned int lastflag;
  __syncthreads();
  if (t == 0) {
    __threadfence();
    unsigned int old = atomicAdd(done, 1u);
    lastflag = (old == 64u * 6u - 1u) ? 1u : 0u;
  }
  __syncthreads();
  if (lastflag) {
    double s = 0.0;
    for (int c2 = t; c2 < COMPS; c2 += 256) {
      float r = __hip_atomic_load(&rowsq[c2], __ATOMIC_RELAXED,
                                  __HIP_MEMORY_SCOPE_AGENT);
      s += sqrt((double)r);
    }
#pragma unroll
    for (int o = 32; o; o >>= 1) s += __shfl_down(s, o);
    __shared__ double red[4];
    if ((t & 63) == 0) red[t >> 6] = s;
    __syncthreads();
    if (t == 0) out[0] = (float)(red[0] + red[1] + red[2] + red[3]);
  }
}

extern "C" void kernel_launch(void* const* d_in, const int* in_sizes, int n_in,
                              void* d_out, int out_size, void* d_ws, size_t ws_size,
                              hipStream_t stream) {
  const float* e = (const float*)d_in[0];       // [8192, 768]
  const float* cont = (const float*)d_in[1];    // [64, 64, 768]
  // d_in[2] (grid_dists) not read: W = E (x) E separable
  const float* sigma = (const float*)d_in[3];   // [1]
  float* out = (float*)d_out;                   // [1 + 4096*768]

  char* ws = (char*)d_ws;
  size_t off = 0;
  auto take = [&](size_t bytes) { char* p = ws + off; off += (bytes + 255) & ~(size_t)255; return p; };

  unsigned long long* packed = (unsigned long long*)take(NB * 8);
  float* freq  = (float*)take(COMPS * 4);
  float* rowsq = (float*)take(COMPS * 4);
  float* cnorm = (float*)take(COMPS * 4);
  float* E     = (float*)take(64 * 64 * 4);
  float* rE    = (float*)take(64 * 4);
  unsigned int* done = (unsigned int*)take(256);
  _Float16* sums = (_Float16*)take((size_t)COMPS * DIM * 2);   // f16 sums
  // union region: {ehi, chi, clo} during GEMM1; T1 aliases chi+clo after
  char* U = take((size_t)NB * DIM * 2 + (size_t)COMPS * DIM * 2 * 2);
  _Float16* ehi = (_Float16*)U;
  _Float16* chi = (_Float16*)(U + (size_t)NB * DIM * 2);
  _Float16* clo = (_Float16*)(U + (size_t)NB * DIM * 2 + (size_t)COMPS * DIM * 2);
  float* T1 = (float*)(U + (size_t)NB * DIM * 2);   // 12.58MB = chi+clo region

  k_prep<<<PREP_GRID, 256, 0, stream>>>(e, cont, sigma, ehi, chi, clo,
                                        cnorm, E, rE, sums, freq, rowsq,
                                        packed, done);
  k_gemm1<<<dim3(NB / 128, COMPS / 128), 256, 0, stream>>>(ehi, chi, clo, cnorm, packed);
  k_scatter<<<NB, 192, 0, stream>>>(ehi, packed, freq, (__half2*)sums);
  k_t1<<<dim3(64, 6), 256, 0, stream>>>(sums, freq, cont, E, T1);
  k_wnum<<<dim3(64, 6), 256, 0, stream>>>(T1, E, rE, freq, cont, out, rowsq, done);
}